// Round 1
// baseline (17111.903 us; speedup 1.0000x reference)
//
#include <hip/hip_runtime.h>
#include <stdint.h>

#define NPIX   (16 * 512 * 512)   // 4,194,304
#define IMG    (512 * 512)
#define NB     16
#define ITERS  200

// ---- workspace header ----
struct Hdr {
    unsigned int umax;       // max(predict) as uint bits (nonneg float order == uint order)
    unsigned int n_unique;
    unsigned int pad[14];
    float num[NB];
    float den[NB];
};
#define HDR_BYTES 256
#define BM_WORDS  (NPIX / 32)    // 131072 words = 512 KB bitmap

// ---------- global max of predict ----------
__global__ void k_max(const float* __restrict__ p, unsigned int* umax, int n) {
    unsigned int m = 0;
    for (int i = blockIdx.x * blockDim.x + threadIdx.x; i < n; i += gridDim.x * blockDim.x)
        m = max(m, __float_as_uint(p[i]));
    for (int o = 32; o > 0; o >>= 1)
        m = max(m, (unsigned int)__shfl_down(m, o, 64));
    __shared__ unsigned int sm[4];
    int lane = threadIdx.x & 63, w = threadIdx.x >> 6;
    if (lane == 0) sm[w] = m;
    __syncthreads();
    if (threadIdx.x == 0) {
        unsigned int r = max(max(sm[0], sm[1]), max(sm[2], sm[3]));
        atomicMax(umax, r);
    }
}

// ---------- init labels (+fused dice partial sums) ----------
// label = i if predict[i] > thr else -1   (background encoded as -1; mask <=> label>=0)
__global__ void k_init(const float* __restrict__ pr, const float* __restrict__ tg,
                       const unsigned int* __restrict__ umax,
                       int* __restrict__ lab, float* num, float* den) {
    int i = blockIdx.x * 256 + threadIdx.x;
    float thr = __uint_as_float(*umax) * 0.5f;
    float p = pr[i], t = tg[i];
    lab[i] = (p > thr) ? i : -1;

    __shared__ float sa[256], sd[256];
    sa[threadIdx.x] = p * t;
    sd[threadIdx.x] = p * p + t * t;
    __syncthreads();
    for (int s = 128; s > 0; s >>= 1) {
        if (threadIdx.x < s) {
            sa[threadIdx.x] += sa[threadIdx.x + s];
            sd[threadIdx.x] += sd[threadIdx.x + s];
        }
        __syncthreads();
    }
    if (threadIdx.x == 0) {
        int b = (blockIdx.x * 256) / IMG;   // block never straddles a batch (256 | IMG)
        atomicAdd(&num[b], sa[0]);
        atomicAdd(&den[b], sd[0]);
    }
}

// ---------- one masked 3x3 max-propagation step ----------
__global__ __launch_bounds__(256) void k_prop(const int* __restrict__ in, int* __restrict__ out) {
    int x = blockIdx.x * 64 + threadIdx.x;   // 0..511
    int y = blockIdx.y * 4 + threadIdx.y;    // 0..511
    int b = blockIdx.z;
    const int* img = in + b * IMG;
    int idx = (y << 9) + x;
    int v = img[idx];
    if (v >= 0) {                             // masked pixel (invariant: label>=0 <=> mask)
        bool xm = x > 0, xp = x < 511;
        if (y > 0) {
            const int* r = img + idx - 512;
            if (xm) v = max(v, r[-1]);
            v = max(v, r[0]);
            if (xp) v = max(v, r[1]);
        }
        if (xm) v = max(v, img[idx - 1]);
        if (xp) v = max(v, img[idx + 1]);
        if (y < 511) {
            const int* r = img + idx + 512;
            if (xm) v = max(v, r[-1]);
            v = max(v, r[0]);
            if (xp) v = max(v, r[1]);
        }
    }
    out[b * IMG + idx] = v;
}

// ---------- presence bitmap over final label values ----------
__global__ void k_bits(const int* __restrict__ lab, unsigned int* __restrict__ bm) {
    int i = blockIdx.x * 256 + threadIdx.x;
    int v = lab[i];
    unsigned int key = (v < 0) ? 0u : (unsigned int)v;   // -1 (bg) -> value 0.0 in reference
    if (i > 0) {
        int pv = lab[i - 1];
        unsigned int pk = (pv < 0) ? 0u : (unsigned int)pv;
        if (pk == key) return;   // run-length dedup: first element of each run sets the bit
    }
    atomicOr(&bm[key >> 5], 1u << (key & 31));
}

// ---------- popcount reduce ----------
__global__ void k_popc(const unsigned int* __restrict__ bm, unsigned int* nuniq, int words) {
    unsigned int c = 0;
    for (int i = blockIdx.x * blockDim.x + threadIdx.x; i < words; i += gridDim.x * blockDim.x)
        c += __popc(bm[i]);
    for (int o = 32; o > 0; o >>= 1)
        c += __shfl_down(c, o, 64);
    __shared__ unsigned int sc[4];
    int lane = threadIdx.x & 63, w = threadIdx.x >> 6;
    if (lane == 0) sc[w] = c;
    __syncthreads();
    if (threadIdx.x == 0)
        atomicAdd(nuniq, sc[0] + sc[1] + sc[2] + sc[3]);
}

// ---------- epilogue ----------
__global__ void k_final(const unsigned int* __restrict__ nuniq,
                        const float* __restrict__ num, const float* __restrict__ den,
                        float* __restrict__ out) {
    float loss = 0.0f;
    for (int b = 0; b < NB; ++b)
        loss += 1.0f - (num[b] + 1.0f) / (den[b] + 1.0f);
    loss *= (1.0f / NB);
    float penalty = (float)(*nuniq) / (float)NB;
    if (penalty < 1.0f) penalty = (float)NB;   // jnp.where(penalty < 1, B, penalty)
    penalty = fminf(penalty, (float)NB);       // jnp.minimum(penalty, B)
    out[0] = loss * penalty;
}

extern "C" void kernel_launch(void* const* d_in, const int* in_sizes, int n_in,
                              void* d_out, int out_size, void* d_ws, size_t ws_size,
                              hipStream_t stream) {
    const float* predict = (const float*)d_in[0];
    const float* target  = (const float*)d_in[1];
    float* out = (float*)d_out;

    char* ws = (char*)d_ws;
    Hdr* hdr = (Hdr*)ws;
    int* labA = (int*)(ws + HDR_BYTES);
    int* labB = labA + NPIX;
    unsigned int* bm = (unsigned int*)(ws + HDR_BYTES + (size_t)2 * NPIX * sizeof(int));

    hipMemsetAsync(hdr, 0, HDR_BYTES, stream);
    hipMemsetAsync(bm, 0, BM_WORDS * sizeof(unsigned int), stream);

    k_max<<<2048, 256, 0, stream>>>(predict, &hdr->umax, NPIX);
    k_init<<<NPIX / 256, 256, 0, stream>>>(predict, target, &hdr->umax, labA, hdr->num, hdr->den);

    dim3 pb(64, 4, 1), pg(8, 128, 16);
    int* a = labA;
    int* b = labB;
    for (int it = 0; it < ITERS; ++it) {
        k_prop<<<pg, pb, 0, stream>>>(a, b);
        int* t = a; a = b; b = t;
    }
    // ITERS even -> final labels in labA (== a)

    k_bits<<<NPIX / 256, 256, 0, stream>>>(a, bm);
    k_popc<<<512, 256, 0, stream>>>(bm, &hdr->n_unique, BM_WORDS);
    k_final<<<1, 1, 0, stream>>>(&hdr->n_unique, hdr->num, hdr->den, out);
}

// Round 2
// 2788.396 us; speedup vs baseline: 6.1368x; 6.1368x over previous
//
#include <hip/hip_runtime.h>
#include <stdint.h>
#include <limits.h>

#define NPIX   (16 * 512 * 512)   // 4,194,304
#define IMG    (512 * 512)
#define NB     16
#define ITERS  200

// ---- workspace header ----
struct Hdr {
    unsigned int umax;       // max(predict) as uint bits (nonneg float order == uint order)
    unsigned int n_unique;
    unsigned int pad[14];
    float num[NB];
    float den[NB];
};
#define HDR_BYTES 256
#define BM_WORDS  (NPIX / 32)    // 131072 words = 512 KB bitmap

// ---------- global max of predict ----------
__global__ void k_max(const float* __restrict__ p, unsigned int* umax, int n) {
    unsigned int m = 0;
    for (int i = blockIdx.x * blockDim.x + threadIdx.x; i < n; i += gridDim.x * blockDim.x)
        m = max(m, __float_as_uint(p[i]));
    for (int o = 32; o > 0; o >>= 1)
        m = max(m, (unsigned int)__shfl_down(m, o, 64));
    __shared__ unsigned int sm[4];
    int lane = threadIdx.x & 63, w = threadIdx.x >> 6;
    if (lane == 0) sm[w] = m;
    __syncthreads();
    if (threadIdx.x == 0) {
        unsigned int r = max(max(sm[0], sm[1]), max(sm[2], sm[3]));
        atomicMax(umax, r);
    }
}

// ---------- init labels (+fused dice partial sums) ----------
// label = i if predict[i] > thr else -1   (background encoded as -1; mask <=> label>=0)
__global__ void k_init(const float* __restrict__ pr, const float* __restrict__ tg,
                       const unsigned int* __restrict__ umax,
                       int* __restrict__ lab, float* num, float* den) {
    int i = blockIdx.x * 256 + threadIdx.x;
    float thr = __uint_as_float(*umax) * 0.5f;
    float p = pr[i], t = tg[i];
    lab[i] = (p > thr) ? i : -1;

    __shared__ float sa[256], sd[256];
    sa[threadIdx.x] = p * t;
    sd[threadIdx.x] = p * p + t * t;
    __syncthreads();
    for (int s = 128; s > 0; s >>= 1) {
        if (threadIdx.x < s) {
            sa[threadIdx.x] += sa[threadIdx.x + s];
            sd[threadIdx.x] += sd[threadIdx.x + s];
        }
        __syncthreads();
    }
    if (threadIdx.x == 0) {
        int b = (blockIdx.x * 256) / IMG;   // block never straddles a batch (256 | IMG)
        atomicAdd(&num[b], sa[0]);
        atomicAdd(&den[b], sd[0]);
    }
}

// ---------- one masked 3x3 max-propagation step (4 px/thread, int4) ----------
__global__ __launch_bounds__(256) void k_prop(const int* __restrict__ in, int* __restrict__ out) {
    int tx = blockIdx.x * 64 + threadIdx.x;    // 0..127
    int x0 = tx << 2;                          // 0,4,...,508
    int y  = blockIdx.y * 4 + threadIdx.y;     // 0..511
    int b  = blockIdx.z;
    const int* img = in + b * IMG;
    int idx = (y << 9) + x0;
    const int NEG = INT_MIN;
    bool xm = (x0 > 0), xp = (x0 < 508);

    int4 c = *(const int4*)(img + idx);
    int lc = xm ? img[idx - 1] : NEG;
    int rc = xp ? img[idx + 4] : NEG;

    int4 u; int lu, ru;
    if (y > 0) {
        u  = *(const int4*)(img + idx - 512);
        lu = xm ? img[idx - 513] : NEG;
        ru = xp ? img[idx - 508] : NEG;
    } else { u = make_int4(NEG, NEG, NEG, NEG); lu = NEG; ru = NEG; }

    int4 d; int ld, rd;
    if (y < 511) {
        d  = *(const int4*)(img + idx + 512);
        ld = xm ? img[idx + 511] : NEG;
        rd = xp ? img[idx + 516] : NEG;
    } else { d = make_int4(NEG, NEG, NEG, NEG); ld = NEG; rd = NEG; }

    // horizontal 3-maxes per row
    int hc0 = max(max(lc,  c.x), c.y), hc1 = max(max(c.x, c.y), c.z);
    int hc2 = max(max(c.y, c.z), c.w), hc3 = max(max(c.z, c.w), rc);
    int hu0 = max(max(lu,  u.x), u.y), hu1 = max(max(u.x, u.y), u.z);
    int hu2 = max(max(u.y, u.z), u.w), hu3 = max(max(u.z, u.w), ru);
    int hd0 = max(max(ld,  d.x), d.y), hd1 = max(max(d.x, d.y), d.z);
    int hd2 = max(max(d.y, d.z), d.w), hd3 = max(max(d.z, d.w), rd);

    int4 o;
    o.x = (c.x >= 0) ? max(hc0, max(hu0, hd0)) : c.x;
    o.y = (c.y >= 0) ? max(hc1, max(hu1, hd1)) : c.y;
    o.z = (c.z >= 0) ? max(hc2, max(hu2, hd2)) : c.z;
    o.w = (c.w >= 0) ? max(hc3, max(hu3, hd3)) : c.w;
    *(int4*)(out + b * IMG + idx) = o;
}

// ---------- presence bitmap: run-head + block dedup + test-and-set ----------
__global__ __launch_bounds__(256) void k_bits(const int* __restrict__ lab,
                                              unsigned int* __restrict__ bm) {
    int i = blockIdx.x * 256 + threadIdx.x;
    int v = lab[i];
    unsigned int key = (v < 0) ? 0u : (unsigned int)v;   // bg(-1) -> value 0.0 in reference
    bool cand = true;
    if (i > 0) {                                          // run-head check (cross-block via global)
        int pv = lab[i - 1];
        unsigned int pk = (pv < 0) ? 0u : (unsigned int)pv;
        cand = (pk != key);
    }
    __shared__ unsigned int sk[256];
    sk[threadIdx.x] = cand ? key : 0xFFFFFFFFu;           // keys < 2^23, sentinel safe
    __syncthreads();
    if (cand) {                                           // first occurrence within block
        for (int j = 0; j < threadIdx.x; ++j)
            if (sk[j] == key) { cand = false; break; }
    }
    if (cand) {
        unsigned int w = bm[key >> 5];                    // test (stale read only costs a redundant atomic)
        if (!((w >> (key & 31)) & 1u))
            atomicOr(&bm[key >> 5], 1u << (key & 31));
    }
}

// ---------- popcount reduce ----------
__global__ void k_popc(const unsigned int* __restrict__ bm, unsigned int* nuniq, int words) {
    unsigned int c = 0;
    for (int i = blockIdx.x * blockDim.x + threadIdx.x; i < words; i += gridDim.x * blockDim.x)
        c += __popc(bm[i]);
    for (int o = 32; o > 0; o >>= 1)
        c += __shfl_down(c, o, 64);
    __shared__ unsigned int sc[4];
    int lane = threadIdx.x & 63, w = threadIdx.x >> 6;
    if (lane == 0) sc[w] = c;
    __syncthreads();
    if (threadIdx.x == 0)
        atomicAdd(nuniq, sc[0] + sc[1] + sc[2] + sc[3]);
}

// ---------- epilogue ----------
__global__ void k_final(const unsigned int* __restrict__ nuniq,
                        const float* __restrict__ num, const float* __restrict__ den,
                        float* __restrict__ out) {
    float loss = 0.0f;
    for (int b = 0; b < NB; ++b)
        loss += 1.0f - (num[b] + 1.0f) / (den[b] + 1.0f);
    loss *= (1.0f / NB);
    float penalty = (float)(*nuniq) / (float)NB;
    if (penalty < 1.0f) penalty = (float)NB;   // jnp.where(penalty < 1, B, penalty)
    penalty = fminf(penalty, (float)NB);       // jnp.minimum(penalty, B)
    out[0] = loss * penalty;
}

extern "C" void kernel_launch(void* const* d_in, const int* in_sizes, int n_in,
                              void* d_out, int out_size, void* d_ws, size_t ws_size,
                              hipStream_t stream) {
    const float* predict = (const float*)d_in[0];
    const float* target  = (const float*)d_in[1];
    float* out = (float*)d_out;

    char* ws = (char*)d_ws;
    Hdr* hdr = (Hdr*)ws;
    int* labA = (int*)(ws + HDR_BYTES);
    int* labB = labA + NPIX;
    unsigned int* bm = (unsigned int*)(ws + HDR_BYTES + (size_t)2 * NPIX * sizeof(int));

    hipMemsetAsync(hdr, 0, HDR_BYTES, stream);
    hipMemsetAsync(bm, 0, BM_WORDS * sizeof(unsigned int), stream);

    k_max<<<2048, 256, 0, stream>>>(predict, &hdr->umax, NPIX);
    k_init<<<NPIX / 256, 256, 0, stream>>>(predict, target, &hdr->umax, labA, hdr->num, hdr->den);

    dim3 pb(64, 4, 1), pg(2, 128, 16);   // 4 px/thread in x
    int* a = labA;
    int* b = labB;
    for (int it = 0; it < ITERS; ++it) {
        k_prop<<<pg, pb, 0, stream>>>(a, b);
        int* t = a; a = b; b = t;
    }
    // ITERS even -> final labels in labA (== a)

    k_bits<<<NPIX / 256, 256, 0, stream>>>(a, bm);
    k_popc<<<512, 256, 0, stream>>>(bm, &hdr->n_unique, BM_WORDS);
    k_final<<<1, 1, 0, stream>>>(&hdr->n_unique, hdr->num, hdr->den, out);
}

// Round 3
// 1136.287 us; speedup vs baseline: 15.0595x; 2.4540x over previous
//
#include <hip/hip_runtime.h>
#include <stdint.h>
#include <limits.h>

#define NPIX   (16 * 512 * 512)   // 4,194,304
#define IMG    (512 * 512)
#define NB     16
#define ITERS  200

#define TILE   80     // 64 core + 2*8 halo
#define CORE   64
#define HALO   8
#define KIT    8      // fused iterations per launch; 200 = 25 * 8

// ---- workspace header ----
struct Hdr {
    unsigned int umax;       // max(predict) as uint bits (nonneg float order == uint order)
    unsigned int n_unique;
    unsigned int pad[14];
    float num[NB];
    float den[NB];
};
#define HDR_BYTES 256
#define BM_WORDS  (NPIX / 32)    // 131072 words = 512 KB bitmap

// ---------- global max of predict ----------
__global__ void k_max(const float* __restrict__ p, unsigned int* umax, int n) {
    unsigned int m = 0;
    for (int i = blockIdx.x * blockDim.x + threadIdx.x; i < n; i += gridDim.x * blockDim.x)
        m = max(m, __float_as_uint(p[i]));
    for (int o = 32; o > 0; o >>= 1)
        m = max(m, (unsigned int)__shfl_down(m, o, 64));
    __shared__ unsigned int sm[4];
    int lane = threadIdx.x & 63, w = threadIdx.x >> 6;
    if (lane == 0) sm[w] = m;
    __syncthreads();
    if (threadIdx.x == 0) {
        unsigned int r = max(max(sm[0], sm[1]), max(sm[2], sm[3]));
        atomicMax(umax, r);
    }
}

// ---------- init labels (+fused dice partial sums) ----------
__global__ void k_init(const float* __restrict__ pr, const float* __restrict__ tg,
                       const unsigned int* __restrict__ umax,
                       int* __restrict__ lab, float* num, float* den) {
    int i = blockIdx.x * 256 + threadIdx.x;
    float thr = __uint_as_float(*umax) * 0.5f;
    float p = pr[i], t = tg[i];
    lab[i] = (p > thr) ? i : -1;

    __shared__ float sa[256], sd[256];
    sa[threadIdx.x] = p * t;
    sd[threadIdx.x] = p * p + t * t;
    __syncthreads();
    for (int s = 128; s > 0; s >>= 1) {
        if (threadIdx.x < s) {
            sa[threadIdx.x] += sa[threadIdx.x + s];
            sd[threadIdx.x] += sd[threadIdx.x + s];
        }
        __syncthreads();
    }
    if (threadIdx.x == 0) {
        int b = (blockIdx.x * 256) / IMG;
        atomicAdd(&num[b], sa[0]);
        atomicAdd(&den[b], sd[0]);
    }
}

// ---------- fused 8-iteration masked 3x3 max-propagation on an LDS tile ----------
// Tile: 80x80 loaded (64x64 core + 8 halo). Halo-8 supports exactly 8 iters:
// edge garbage (monotonically too-small) travels 1 px/iter, never reaches core.
// Separable: out = mask ? hmax3(vmax3(v)) : -1, gate via (center>>31)|h since bg == -1.
#define MAX3(a, b, c) max(max((a), (b)), (c))

__global__ __launch_bounds__(256) void k_prop8(const int* __restrict__ in, int* __restrict__ out) {
    __shared__ int T[TILE * TILE];
    const int tid = threadIdx.x;
    const int bimg = blockIdx.z;
    const int gx0 = blockIdx.x * CORE - HALO;
    const int gy0 = blockIdx.y * CORE - HALO;
    const int* img = in + bimg * IMG;

    // ---- load 80x80 tile, int4 units, -1 outside image ----
    for (int u = tid; u < (TILE * TILE / 4); u += 256) {
        int r  = u / (TILE / 4);
        int c4 = u % (TILE / 4);
        int gy = gy0 + r;
        int gx = gx0 + c4 * 4;
        int4 val;
        if (gy >= 0 && gy < 512 && gx >= 0 && gx < 512)
            val = *(const int4*)(img + (gy << 9) + gx);
        else
            val = make_int4(-1, -1, -1, -1);
        *(int4*)&T[r * TILE + c4 * 4] = val;
    }
    __syncthreads();

    const bool active = (tid < 200);           // 20 col-units x 10 row-units
    const int cu = tid % 20, ru = tid / 20;
    const int x0 = cu * 4;
    const int yr = ru * 8;
    int4 O[8];

#define LOAD_ROW(y, V, VL, VR) do {                                         \
        int _y = (y);                                                       \
        if (_y >= 0 && _y < TILE) {                                         \
            V  = *(const int4*)&T[_y * TILE + x0];                          \
            VL = (x0 > 0)        ? T[_y * TILE + x0 - 1] : -1;              \
            VR = (x0 < TILE - 4) ? T[_y * TILE + x0 + 4] : -1;              \
        } else { V = make_int4(-1, -1, -1, -1); VL = -1; VR = -1; }         \
    } while (0)

    for (int it = 0; it < KIT; ++it) {
        if (active) {
            int4 A, B, C; int Al, Ar, Bl, Br, Cl, Cr;
            LOAD_ROW(yr - 1, A, Al, Ar);
            LOAD_ROW(yr,     B, Bl, Br);
#pragma unroll
            for (int j = 0; j < 8; ++j) {
                LOAD_ROW(yr + j + 1, C, Cl, Cr);
                int4 col;
                col.x = MAX3(A.x, B.x, C.x);
                col.y = MAX3(A.y, B.y, C.y);
                col.z = MAX3(A.z, B.z, C.z);
                col.w = MAX3(A.w, B.w, C.w);
                int cl = MAX3(Al, Bl, Cl);
                int cr = MAX3(Ar, Br, Cr);
                int4 h;
                h.x = MAX3(cl,    col.x, col.y);
                h.y = MAX3(col.x, col.y, col.z);
                h.z = MAX3(col.y, col.z, col.w);
                h.w = MAX3(col.z, col.w, cr);
                O[j].x = h.x | (B.x >> 31);   // bg stays exactly -1
                O[j].y = h.y | (B.y >> 31);
                O[j].z = h.z | (B.z >> 31);
                O[j].w = h.w | (B.w >> 31);
                A = B; Al = Bl; Ar = Br;
                B = C; Bl = Cl; Br = Cr;
            }
        }
        __syncthreads();
        if (active) {
#pragma unroll
            for (int j = 0; j < 8; ++j)
                *(int4*)&T[(yr + j) * TILE + x0] = O[j];
        }
        __syncthreads();
    }

    // ---- write back 64x64 core ----
    int* oimg = out + bimg * IMG;
    for (int u = tid; u < (CORE * CORE / 4); u += 256) {
        int r  = u / (CORE / 4);
        int c4 = u % (CORE / 4);
        int4 val = *(const int4*)&T[(HALO + r) * TILE + HALO + c4 * 4];
        *(int4*)(oimg + ((blockIdx.y * CORE + r) << 9) + blockIdx.x * CORE + c4 * 4) = val;
    }
#undef LOAD_ROW
}

// ---------- presence bitmap: run-head + O(1) hash block-dedup + test-and-set ----------
__global__ __launch_bounds__(256) void k_bits(const int* __restrict__ lab,
                                              unsigned int* __restrict__ bm) {
    int i = blockIdx.x * 256 + threadIdx.x;
    int tid = threadIdx.x;
    int v = lab[i];
    unsigned int key = (v < 0) ? 0u : (unsigned int)v;   // bg(-1) -> value 0.0 in reference
    bool cand = true;
    if (i > 0) {                                          // run-head check
        int pv = lab[i - 1];
        unsigned int pk = (pv < 0) ? 0u : (unsigned int)pv;
        cand = (pk != key);
    }
    __shared__ unsigned int sk[256];
    __shared__ int slot[256];
    sk[tid] = key;
    if (cand) slot[key & 255] = tid;                      // last writer wins
    __syncthreads();
    if (cand) {
        int w = slot[key & 255];
        if (w != tid && sk[w] == key) cand = false;       // winner with same key exists
    }
    if (cand) {
        unsigned int word = bm[key >> 5];                 // test (stale read = harmless extra atomic)
        if (!((word >> (key & 31)) & 1u))
            atomicOr(&bm[key >> 5], 1u << (key & 31));
    }
}

// ---------- popcount reduce ----------
__global__ void k_popc(const unsigned int* __restrict__ bm, unsigned int* nuniq, int words) {
    unsigned int c = 0;
    for (int i = blockIdx.x * blockDim.x + threadIdx.x; i < words; i += gridDim.x * blockDim.x)
        c += __popc(bm[i]);
    for (int o = 32; o > 0; o >>= 1)
        c += __shfl_down(c, o, 64);
    __shared__ unsigned int sc[4];
    int lane = threadIdx.x & 63, w = threadIdx.x >> 6;
    if (lane == 0) sc[w] = c;
    __syncthreads();
    if (threadIdx.x == 0)
        atomicAdd(nuniq, sc[0] + sc[1] + sc[2] + sc[3]);
}

// ---------- epilogue ----------
__global__ void k_final(const unsigned int* __restrict__ nuniq,
                        const float* __restrict__ num, const float* __restrict__ den,
                        float* __restrict__ out) {
    float loss = 0.0f;
    for (int b = 0; b < NB; ++b)
        loss += 1.0f - (num[b] + 1.0f) / (den[b] + 1.0f);
    loss *= (1.0f / NB);
    float penalty = (float)(*nuniq) / (float)NB;
    if (penalty < 1.0f) penalty = (float)NB;   // jnp.where(penalty < 1, B, penalty)
    penalty = fminf(penalty, (float)NB);       // jnp.minimum(penalty, B)
    out[0] = loss * penalty;
}

extern "C" void kernel_launch(void* const* d_in, const int* in_sizes, int n_in,
                              void* d_out, int out_size, void* d_ws, size_t ws_size,
                              hipStream_t stream) {
    const float* predict = (const float*)d_in[0];
    const float* target  = (const float*)d_in[1];
    float* out = (float*)d_out;

    char* ws = (char*)d_ws;
    Hdr* hdr = (Hdr*)ws;
    int* labA = (int*)(ws + HDR_BYTES);
    int* labB = labA + NPIX;
    unsigned int* bm = (unsigned int*)(ws + HDR_BYTES + (size_t)2 * NPIX * sizeof(int));

    hipMemsetAsync(hdr, 0, HDR_BYTES, stream);
    hipMemsetAsync(bm, 0, BM_WORDS * sizeof(unsigned int), stream);

    k_max<<<2048, 256, 0, stream>>>(predict, &hdr->umax, NPIX);
    k_init<<<NPIX / 256, 256, 0, stream>>>(predict, target, &hdr->umax, labA, hdr->num, hdr->den);

    dim3 pb(256, 1, 1), pg(8, 8, 16);   // 64x64 core tiles
    int* a = labA;
    int* b = labB;
    for (int it = 0; it < ITERS / KIT; ++it) {   // 25 launches x 8 fused iters
        k_prop8<<<pg, pb, 0, stream>>>(a, b);
        int* t = a; a = b; b = t;
    }
    // 25 launches (odd) -> final labels in labB == a

    k_bits<<<NPIX / 256, 256, 0, stream>>>(a, bm);
    k_popc<<<512, 256, 0, stream>>>(bm, &hdr->n_unique, BM_WORDS);
    k_final<<<1, 1, 0, stream>>>(&hdr->n_unique, hdr->num, hdr->den, out);
}